// Round 4
// baseline (557.410 us; speedup 1.0000x reference)
//
#include <hip/hip_runtime.h>
#include <hip/hip_bf16.h>

#define CIN   64
#define COUT  64
#define TT    512
#define FF    161
#define KTOT  576          // 9 * 64
#define TFSTR (TT*FF)      // 82432
#define FP_   168          // padded f dim of X2: fp = f+1, zeros at fp=0 and fp>=162

#define W2_BYTES ((size_t)FF*COUT*KTOT*2)            // 11,870,208
#define X2_BYTES ((size_t)8*TT*FP_*64*2)             // 88,080,384
#define PW_BLOCKS 5796                               // 161*9216/256 u16x4 quads

typedef __bf16 bf16x8 __attribute__((ext_vector_type(8)));
typedef float  f32x4  __attribute__((ext_vector_type(4)));
typedef unsigned short u16x8 __attribute__((ext_vector_type(8)));
typedef unsigned short u16x4 __attribute__((ext_vector_type(4)));
typedef float f2u __attribute__((ext_vector_type(2), aligned(4)));

__device__ __forceinline__ unsigned short f2bf(float v) {
    union { float f; unsigned int u; } c; c.f = v;
    unsigned int u = c.u + 0x7FFFu + ((c.u >> 16) & 1u);   // RNE
    return (unsigned short)(u >> 16);
}

// ---- fused prep: blocks [0, PW_BLOCKS) repack weights; rest transpose x ----
// weights: W2[f][o][k], k=(kh*3+kw)*64+i. Dest-coalesced u16x4 stores.
// x: (b,i,t,f) f32 -> X2[b][t][fp][i] bf16, fp=f+1 (zero pad cols).
__global__ __launch_bounds__(256) void prep_fused(
    const float* __restrict__ ksrc, unsigned short* __restrict__ w2,
    const float* __restrict__ x, unsigned short* __restrict__ x2)
{
    __shared__ unsigned short Xs[64][170];
    int bx = blockIdx.x;
    int tid = threadIdx.x;

    if (bx < PW_BLOCKS) {
        int g  = bx*256 + tid;          // u16x4 index
        int f  = g / 9216;
        int j  = g - f*9216;
        int o  = j / 144;
        int r  = j - o*144;
        int q  = r >> 4;                // tap
        int i4 = (r & 15) * 4;
        u16x4 v;
        #pragma unroll
        for (int e = 0; e < 4; ++e)
            v[e] = f2bf(ksrc[((size_t)(o*64 + i4 + e)*FF + f)*9 + q]);
        *(u16x4*)&w2[(size_t)f*36864 + j*4] = v;
        return;
    }

    int bt = bx - PW_BLOCKS;            // 0..4095
    int b  = bt >> 9;
    int t  = bt & 511;
    const float* xb = x + (size_t)b*CIN*TFSTR + (size_t)t*FF;
    #pragma unroll
    for (int k = 0; k < 21; ++k) {
        int s = tid + k*256;
        if (s < 5184) {                 // 64 i * 81 slots
            int i = s / 81;
            int u = s - i*81;
            const float* p = xb + (size_t)i*TFSTR + 2*u;
            if (u < 80) {
                f2u v = *(const f2u*)p;
                unsigned pk = (unsigned)f2bf(v.x) | ((unsigned)f2bf(v.y) << 16);
                *(unsigned*)&Xs[i][2*u] = pk;
            } else {
                Xs[i][160] = f2bf(*p);
            }
        }
    }
    __syncthreads();
    unsigned short* ob = x2 + (size_t)bt * FP_ * 64;
    #pragma unroll
    for (int k = 0; k < 6; ++k) {
        int s = tid + k*256;
        if (s < 1344) {                 // 168 fp rows * 8 chunks
            int fp = s >> 3;
            int j  = s & 7;
            u16x8 v = {0,0,0,0,0,0,0,0};
            if (fp >= 1 && fp < 162) {
                int f = fp - 1;
                #pragma unroll
                for (int e = 0; e < 8; ++e) v[e] = Xs[j*8 + e][f];
            }
            *(u16x8*)&ob[fp*64 + j*8] = v;
        }
    }
}

// ---- main: block = 16 o x 64 t, loops ALL f in 11 chunks of 16 ----
// 8 waves; wave wv owns f-pair (f0+2wv, f0+2wv+1); double-buffered LDS,
// 2 i-half phases per chunk. Stores are block-sequential in f -> full-line
// completion inside one block's L2 residency (kills partial-line RMW).
__global__ __launch_bounds__(512, 2) void conv_mfma4(
    const unsigned short* __restrict__ x2, const unsigned short* __restrict__ w2,
    const float* __restrict__ bias, float* __restrict__ out)
{
    int bx = blockIdx.x;                // 256 blocks
    int b  = bx & 7;                    // XCD = batch
    int s  = bx >> 3;
    int tc = s >> 2;
    int og = s & 3;
    int t0 = tc * 64;
    int o0 = og * 16;

    // LDS rows = fp*66 + tl (fp 0..17, tl 0..65), 32 bf16 (one i-half) per row
    __shared__ alignas(16) unsigned short As[2][38016];   // 152,064 B

    int tid = threadIdx.x;
    int l   = tid & 63;
    int wv  = tid >> 6;                 // 0..7
    int l15 = l & 15;
    int lq  = l >> 4;
    int fo  = wv * 2;
    int o   = o0 + l15;

    const unsigned short* zrow = x2 + 167*64;   // guaranteed-zero row

    auto stage = [&](int c, int ih, int bufsel) {
        int f0n = c * 16;
        #pragma unroll
        for (int it = 0; it < 10; ++it) {
            int idx = tid + it*512;
            if (idx < 4752) {           // 18*66 rows * 4 slots
                int row = idx >> 2;
                int j   = idx & 3;
                int fp  = row / 66;
                int tl  = row - fp*66;
                int gt  = t0 - 1 + tl;
                int fpg = f0n + fp; fpg = fpg > 167 ? 167 : fpg;  // clamp -> zeros
                int key = (tl + fp) & 3;
                const unsigned short* src = (gt >= 0 && gt < TT)
                    ? x2 + (((size_t)b*TT + gt)*FP_ + fpg)*64 + ih*32 + ((j ^ key)*8)
                    : zrow + ih*32 + j*8;
                __builtin_amdgcn_global_load_lds(
                    (const __attribute__((address_space(1))) void*)src,
                    (__attribute__((address_space(3))) void*)(&As[bufsel][idx*8]),
                    16, 0, 0);
            }
        }
    };

    f32x4 acc[2][4];
    stage(0, 0, 0);
    __syncthreads();

    for (int c = 0; c < 11; ++c) {
        int f0 = c * 16;
        #pragma unroll
        for (int ff = 0; ff < 2; ++ff)
            #pragma unroll
            for (int mf = 0; mf < 4; ++mf)
                acc[ff][mf] = (f32x4){0.f, 0.f, 0.f, 0.f};

        #pragma unroll
        for (int ih = 0; ih < 2; ++ih) {
            if (!(c == 10 && ih == 1)) stage(c + ih, ih ^ 1, ih ^ 1);

            const unsigned short* bp = As[ih];
            int fe0 = f0 + fo;     if (fe0 > 160) fe0 = 160;
            int fe1 = f0 + fo + 1; if (fe1 > 160) fe1 = 160;
            const unsigned short* wb0 = w2 + ((size_t)fe0*COUT + o)*KTOT + ih*32 + lq*8;
            const unsigned short* wb1 = w2 + ((size_t)fe1*COUT + o)*KTOT + ih*32 + lq*8;

            #pragma unroll
            for (int dm = 0; dm < 3; ++dm) {
                bf16x8 bw0[3], bw1[3];
                #pragma unroll
                for (int dn = 0; dn < 3; ++dn) {
                    bw0[dn] = *(const bf16x8*)&wb0[(dm*3 + dn)*64];
                    bw1[dn] = *(const bf16x8*)&wb1[(dm*3 + dn)*64];
                }
                #pragma unroll
                for (int mf = 0; mf < 4; ++mf) {
                    int tl = mf*16 + l15 + dm;
                    bf16x8 a4[4];
                    #pragma unroll
                    for (int u = 0; u < 4; ++u) {
                        int fp   = fo + u;
                        int slot = lq ^ ((tl + fp) & 3);
                        a4[u] = *(const bf16x8*)&bp[((fp*66 + tl) << 5) + slot*8];
                    }
                    #pragma unroll
                    for (int dn = 0; dn < 3; ++dn) {
                        acc[0][mf] = __builtin_amdgcn_mfma_f32_16x16x32_bf16(
                            a4[dn],     bw0[dn], acc[0][mf], 0, 0, 0);
                        acc[1][mf] = __builtin_amdgcn_mfma_f32_16x16x32_bf16(
                            a4[dn + 1], bw1[dn], acc[1][mf], 0, 0, 0);
                    }
                }
            }

            if (ih == 1) {
                int fA = f0 + fo;
                if (fA <= 160) {
                    float bvA = bias[o*FF + fA];
                    size_t rowb = ((size_t)b*COUT + o)*TT + t0;
                    if (fA < 160) {
                        float bvB = bias[o*FF + fA + 1];
                        #pragma unroll
                        for (int mf = 0; mf < 4; ++mf)
                            #pragma unroll
                            for (int rr = 0; rr < 4; ++rr) {
                                int t = mf*16 + lq*4 + rr;
                                f2u v = { acc[0][mf][rr] + bvA, acc[1][mf][rr] + bvB };
                                *(f2u*)(out + (rowb + t)*FF + fA) = v;
                            }
                    } else {
                        #pragma unroll
                        for (int mf = 0; mf < 4; ++mf)
                            #pragma unroll
                            for (int rr = 0; rr < 4; ++rr) {
                                int t = mf*16 + lq*4 + rr;
                                out[(rowb + t)*FF + 160] = acc[0][mf][rr] + bvA;
                            }
                    }
                }
            }
            __syncthreads();
        }
    }
}

// ---------------- round-1 fallback (stages directly from f32 x; needs only w2) ----------------
__global__ __launch_bounds__(256) void conv_mfma(
    const float* __restrict__ x, const unsigned short* __restrict__ w2,
    const float* __restrict__ bias, float* __restrict__ out)
{
    int bx = blockIdx.x;
    int r  = bx & 7;
    int q  = bx >> 3;
    int fblk = q % 41;
    int g  = (q / 41) * 8 + r;
    int b  = g >> 3;
    int t0 = (g & 7) * 64;
    int f0 = fblk * 4;

    __shared__ unsigned short Bs[6][66][64];
    int tid = threadIdx.x;

    for (int i = 0; i < 64; i += 4) {
        #pragma unroll
        for (int pp = 0; pp < 2; ++pp) {
            int p = tid + pp*256;
            if (p < 396) {
                int tl = p / 6, fl = p % 6;
                int gt = t0 - 1 + tl;
                int gf = f0 - 1 + fl;
                bool ok = (gt >= 0) && (gt < TT) && (gf >= 0) && (gf < FF);
                const float* xp = x + (((size_t)(b*CIN + i)*TT + gt)*FF + gf);
                float v0 = ok ? xp[0]       : 0.f;
                float v1 = ok ? xp[TFSTR]   : 0.f;
                float v2 = ok ? xp[2*TFSTR] : 0.f;
                float v3 = ok ? xp[3*TFSTR] : 0.f;
                int isw = i ^ (((tl + fl) & 7) << 3);
                ushort4 pk;
                pk.x = f2bf(v0); pk.y = f2bf(v1); pk.z = f2bf(v2); pk.w = f2bf(v3);
                *reinterpret_cast<ushort4*>(&Bs[fl][tl][isw]) = pk;
            }
        }
    }
    __syncthreads();

    int wv = tid >> 6;
    int l  = tid & 63;
    int f  = f0 + wv;
    if (f >= FF) return;

    int l15 = l & 15;
    int lq  = l >> 4;
    f32x4 acc[4][4] = {};
    const unsigned short* wb = w2 + (size_t)f * (COUT * KTOT);

    #pragma unroll
    for (int dm = 0; dm < 3; ++dm)
    #pragma unroll
    for (int dn = 0; dn < 3; ++dn) {
        int fl = wv + dn;
        int kq = (dm*3 + dn) * 64;
        #pragma unroll
        for (int is = 0; is < 2; ++is) {
            int i0 = is*32 + lq*8;
            bf16x8 a[4];
            #pragma unroll
            for (int mf = 0; mf < 4; ++mf) {
                int tl  = mf*16 + l15 + dm;
                int isw = i0 ^ (((tl + fl) & 7) << 3);
                a[mf] = *(const bf16x8*)&Bs[fl][tl][isw];
            }
            int kb = kq + i0;
            #pragma unroll
            for (int nf = 0; nf < 4; ++nf) {
                bf16x8 bfr = *(const bf16x8*)&wb[(size_t)(nf*16 + l15) * KTOT + kb];
                #pragma unroll
                for (int mf = 0; mf < 4; ++mf)
                    acc[mf][nf] = __builtin_amdgcn_mfma_f32_16x16x32_bf16(
                        a[mf], bfr, acc[mf][nf], 0, 0, 0);
            }
        }
    }

    #pragma unroll
    for (int nf = 0; nf < 4; ++nf) {
        int o = nf*16 + l15;
        float bv = bias[o*FF + f];
        size_t obase = (((size_t)b*COUT + o)*TT + t0 + lq*4)*FF + f;
        #pragma unroll
        for (int mf = 0; mf < 4; ++mf)
            #pragma unroll
            for (int rr = 0; rr < 4; ++rr)
                out[obase + (size_t)(mf*16 + rr)*FF] = acc[mf][nf][rr] + bv;
    }
}

extern "C" void kernel_launch(void* const* d_in, const int* in_sizes, int n_in,
                              void* d_out, int out_size, void* d_ws, size_t ws_size,
                              hipStream_t stream)
{
    (void)in_sizes; (void)n_in; (void)out_size;
    const float* x    = (const float*)d_in[0];
    const float* k    = (const float*)d_in[1];
    const float* bias = (const float*)d_in[2];
    float* out = (float*)d_out;
    unsigned short* w2 = (unsigned short*)d_ws;

    bool big = (ws_size >= W2_BYTES + X2_BYTES);
    unsigned short* x2 = (unsigned short*)((char*)d_ws + W2_BYTES);

    prep_fused<<<big ? (PW_BLOCKS + 8*TT) : PW_BLOCKS, 256, 0, stream>>>(k, w2, x, x2);

    if (big) {
        conv_mfma4<<<256, 512, 0, stream>>>(x2, w2, bias, out);     // 1 block/CU
    } else {
        conv_mfma<<<8*41*8, 256, 0, stream>>>(x, w2, bias, out);    // fallback
    }
}